// Round 12
// baseline (148.019 us; speedup 1.0000x reference)
//
#include <hip/hip_runtime.h>
#include <stdint.h>

// SpatialShiftConvBlock (B=8,T=64,N=21,C=128,F=256):
//   xs[b,t,n,c] = x[b,t,(n - c%21) mod 21, c]       (per-channel circular roll)
//   y  = xs @ W (+ b == 0, and bias cancels in BN anyway)
//   y  = (y - mean)*rsqrt(var + 1e-3)*gamma + beta  (BN training stats over B,T,N)
//   out = relu(y)  (float32 output)
//
// R40 == R39 resubmitted (round-11 bench died in infra: "container failed
// twice"; kernel never executed). R38 proved the identical grid-barrier
// geometry safe (512 blocks, 2/CU, passed at 125.6us).
// R39 design: fused kernel KEPT, W-conversion moved back out.
//  R38 post-mortem: k_fused=68us at 4% VALUBusy because every block converted
//  its own W->bf16 frags via 32.8K scattered 4B loads (4-segment wave instrs,
//  issue-serialized per CU, duplicated 512x). The grid barrier itself is cheap
//  (atomics pipeline at the TCC; R37 had identical sum-atomic counts).
//  - k_prep: 16 blocks, ONE frag per thread (scatter conversion ~3us, was
//    4-block/~13us in R37). Also zeroes the 8 partial-sum arrays + barrier ctr.
//  - k_fused: B-frags via 16 coalesced dwordx4/lane from ws (R37's pattern);
//    A bf16 [32][136] LDS pre-shifted (rows 21..31 zero); 32 MFMA; channel
//    sums -> 8-way partial arrays (p=bt&7, 8x less line contention); grid
//    barrier (all 512 blocks co-resident: LDS 10.75KB, 2 blocks/CU trivially
//    fits); phase C: sum partials (agent-scope loads), scale/bias, single
//    post-BN y write. y round-trip (33MB) still eliminated.
//  Frag maps (HW-verified m89): A: row=l&15,k=(l>>4)*8+j; B: col=l&15 same k;
//  C/D: col=l&15,row=(l>>4)*4+reg.
//  ws floats: [0:4096] 8x{256 sums,256 sumsqs}, [4096] ctr, [4352:..] W frags.
//  fillBufferAligned (~42us harness ws re-poison) is an unconditional tax.

#define NPOS 21
#define CIN  128
#define FOUT 256
#define BT   512            // B*T = grid
#define M_TOTAL 10752       // BT*NPOS
#define BN_EPS 1e-3f
#define AROW 136            // A LDS row stride in bf16 (272B: 16B-aligned)
#define PARTS 8
#define WSFRAG 4352         // float offset of W frags in ws (16B aligned)

typedef short v8s __attribute__((ext_vector_type(8)));   // 8 bf16 (4 VGPR)
typedef float v4f __attribute__((ext_vector_type(4)));   // 4 f32 acc

__device__ __forceinline__ uint16_t f2bf_rne(float f) {
    uint32_t u = __builtin_bit_cast(uint32_t, f);
    u += 0x7FFFu + ((u >> 16) & 1u);                     // round-nearest-even
    return (uint16_t)(u >> 16);
}

// 16 blocks x 256: zero stats/ctr; convert W -> bf16 B-frags (1 frag/thread).
__global__ __launch_bounds__(256) void k_prep(const float* __restrict__ W,
                                              float* __restrict__ ws)
{
    const int t = threadIdx.x;
    const int b = blockIdx.x;
    ws[b * 256 + t] = 0.0f;                              // zero [0:4096]
    if (b == 0 && t == 0)
        *(unsigned int*)(ws + 4096) = 0u;                // barrier ctr

    const int q  = b * 256 + t;                          // frag id 0..4095
    const int l  = q & 63;
    const int ks = (q >> 6) & 3;
    const int nt = q >> 8;                               // n-tile 0..15
    const int kb = ks * 32 + (l >> 4) * 8;
    const int col = nt * 16 + (l & 15);
    uint32_t d[4];
    #pragma unroll
    for (int p = 0; p < 4; p++) {
        uint32_t lo = f2bf_rne(W[(size_t)(kb + 2 * p    ) * FOUT + col]);
        uint32_t hi = f2bf_rne(W[(size_t)(kb + 2 * p + 1) * FOUT + col]);
        d[p] = lo | (hi << 16);
    }
    ((uint4*)(ws + WSFRAG))[q] = make_uint4(d[0], d[1], d[2], d[3]);
}

__global__ __launch_bounds__(256, 2) void k_fused(const float* __restrict__ x,
                                                  const float* __restrict__ gamma,
                                                  const float* __restrict__ beta,
                                                  float* __restrict__ y,
                                                  float* ws)
{
    __shared__ uint16_t asB[32 * AROW];    // 8.7 KB bf16 A, pre-shifted
    __shared__ float scL[FOUT];            // sums, then scale
    __shared__ float bsL[FOUT];            // sumsqs, then bias

    const int bt = blockIdx.x;
    const int t  = threadIdx.x;

    // ---------- Phase A: stage shifted bf16 A-slab ----------
    for (int i = t; i < 704; i += 256) {   // zero pad rows 21..31
        int r  = 21 + (i >> 6);
        int c2 = (i & 63) << 1;
        *(uint32_t*)&asB[r * AROW + c2] = 0u;
    }
    const float* xin = x + (size_t)bt * (NPOS * CIN);
    for (int i = t; i < NPOS * CIN; i += 256) {
        float v = xin[i];                  // fully coalesced f32 load
        int r = i >> 7;                    // i = r*128 + c
        int c = i & (CIN - 1);
        int s = c % NPOS;
        int n = r + s; if (n >= NPOS) n -= NPOS;
        asB[n * AROW + c] = f2bf_rne(v);   // asB[n][c] == bf16(xs[n][c])
    }

    const int w     = t >> 6;              // wave id -> channel group w*64
    const int l     = t & 63;
    const int row16 = l & 15;
    const int koct  = l >> 4;

    // B fragments: 16 coalesced dwordx4 per lane (1KB/wave-instr)
    const uint4* wsw = (const uint4*)(ws + WSFRAG);
    v8s bfr[4][4];
    #pragma unroll
    for (int nt = 0; nt < 4; nt++)
        #pragma unroll
        for (int ks = 0; ks < 4; ks++) {
            uint4 u = wsw[(((w * 4 + nt) * 4 + ks) << 6) + l];
            bfr[nt][ks] = __builtin_bit_cast(v8s, u);
        }
    __syncthreads();

    // ---------- Phase B: MFMA + per-channel partial sums ----------
    v4f acc[2][4];
    #pragma unroll
    for (int m = 0; m < 2; m++)
        #pragma unroll
        for (int nt = 0; nt < 4; nt++) acc[m][nt] = (v4f){0.f, 0.f, 0.f, 0.f};

    #pragma unroll
    for (int m = 0; m < 2; m++) {
        v8s afr[4];
        #pragma unroll
        for (int ks = 0; ks < 4; ks++)     // ds_read_b128, 16B-aligned
            afr[ks] = *(const v8s*)&asB[(m * 16 + row16) * AROW + ks * 32 + koct * 8];
        #pragma unroll
        for (int ks = 0; ks < 4; ks++)
            #pragma unroll
            for (int nt = 0; nt < 4; nt++)
                acc[m][nt] = __builtin_amdgcn_mfma_f32_16x16x32_bf16(
                                 afr[ks], bfr[nt][ks], acc[m][nt], 0, 0, 0);
    }

    #pragma unroll
    for (int nt = 0; nt < 4; nt++) {
        float s = 0.f, q = 0.f;
        #pragma unroll
        for (int m = 0; m < 2; m++)
            #pragma unroll
            for (int rg = 0; rg < 4; rg++) {
                float v = acc[m][nt][rg];  // pad rows contribute exactly 0
                s += v; q += v * v;
            }
        s += __shfl_xor(s, 16); s += __shfl_xor(s, 32);
        q += __shfl_xor(q, 16); q += __shfl_xor(q, 32);
        if (l < 16) {
            scL[w * 64 + nt * 16 + l] = s;
            bsL[w * 64 + nt * 16 + l] = q;
        }
    }
    __syncthreads();
    {
        float* part = ws + (bt & (PARTS - 1)) * 512;     // 8-way spread
        atomicAdd(part + t, scL[t]);
        atomicAdd(part + 256 + t, bsL[t]);
    }
    __threadfence();                       // release my atomics
    __syncthreads();

    // ---------- grid-wide barrier (all 512 blocks co-resident) ----------
    if (t == 0) {
        atomicAdd((unsigned int*)(ws + 4096), 1u);
        while (__hip_atomic_load((unsigned int*)(ws + 4096),
                                 __ATOMIC_RELAXED, __HIP_MEMORY_SCOPE_AGENT)
               < (unsigned int)gridDim.x)
            __builtin_amdgcn_s_sleep(8);
    }
    __syncthreads();
    __threadfence();                       // acquire side

    // ---------- Phase C: stats -> scale/bias, normalize in regs, store ----
    {
        float s = 0.f, q = 0.f;
        #pragma unroll
        for (int p = 0; p < PARTS; p++) {  // agent-scope loads bypass L1
            s += __hip_atomic_load(ws + p * 512 + t, __ATOMIC_RELAXED,
                                   __HIP_MEMORY_SCOPE_AGENT);
            q += __hip_atomic_load(ws + p * 512 + 256 + t, __ATOMIC_RELAXED,
                                   __HIP_MEMORY_SCOPE_AGENT);
        }
        const float invM = 1.0f / (float)M_TOTAL;
        float mean = s * invM;
        float var  = fmaf(-mean, mean, q * invM);
        float sc   = rsqrtf(var + BN_EPS) * gamma[t];
        scL[t] = sc;
        bsL[t] = beta[t] - mean * sc;
    }
    __syncthreads();

    float* yout = y + (size_t)bt * (NPOS * FOUT);
    #pragma unroll
    for (int nt = 0; nt < 4; nt++) {
        const int ch = w * 64 + nt * 16 + row16;
        const float sc = scL[ch];
        const float bs = bsL[ch];
        #pragma unroll
        for (int m = 0; m < 2; m++)
            #pragma unroll
            for (int rg = 0; rg < 4; rg++) {
                int gr = m * 16 + koct * 4 + rg;   // C/D: col=row16, row=koct*4+rg
                if (gr < NPOS)
                    yout[(size_t)gr * FOUT + ch] =
                        fmaxf(fmaf(acc[m][nt][rg], sc, bs), 0.0f);
            }
    }
}

// Template-named symbol kept defined (harness-compat; not launched).
extern "C" __global__ void SpatialShiftConvBlock_71923522339050_kernel() {}

extern "C" void kernel_launch(void* const* d_in, const int* in_sizes, int n_in,
                              void* d_out, int out_size, void* d_ws, size_t ws_size,
                              hipStream_t stream) {
    float* y  = (float*)d_out;             // FLOAT32 output
    float* ws = (float*)d_ws;              // partials | ctr | bf16 W frags
    k_prep<<<16, 256, 0, stream>>>((const float*)d_in[1], ws);
    k_fused<<<BT, 256, 0, stream>>>((const float*)d_in[0],
                                    (const float*)d_in[3], (const float*)d_in[4],
                                    y, ws);
}

// Round 13
// 130.578 us; speedup vs baseline: 1.1336x; 1.1336x over previous
//
#include <hip/hip_runtime.h>
#include <stdint.h>

// SpatialShiftConvBlock (B=8,T=64,N=21,C=128,F=256):
//   xs[b,t,n,c] = x[b,t,(n - c%21) mod 21, c]       (per-channel circular roll)
//   y  = xs @ W (+ b == 0, and bias cancels in BN anyway)
//   y  = (y - mean)*rsqrt(var + 1e-3)*gamma + beta  (BN training stats over B,T,N)
//   out = relu(y)  (float32 output)
//
// R41: barrier de-contention. R40 post-mortem: k_fused 95-100us at 1.4%
// VALUBusy with ideal traffic -> the time was the barrier protocol, not work:
// (1) 512 spinners agent-loading the SAME line the 512 arrivals atomicAdd
//     (reader/writer line ping-pong across 8 XCDs serializes arrivals);
// (2) phase C read 16 agent-scope (uncached) loads/thread on a 16KB region
//     (~2M line-requests at the coherent point).
// Fix: flag barrier. Arrival ctr and release flag on SEPARATE lines; spinners
// poll the read-only flag with s_sleep(16) backoff; the releasing block
// (atomicAdd returns 511) alone reads the 8x512 partials, computes sc/bs[256],
// publishes them agent-scope, then sets the flag. Other blocks read 2 floats
// per thread. Phases A/B + single post-BN y write unchanged (absmax 0.03125).
//  ws floats: [0:4096] 8x{256 sums,256 sumsqs}; [4096] ctr; [4160] flag;
//  [4224:4480] sc; [4480:4736] bs; [4864:...] bf16 W frags (16 blocks'
//  k_prep zeroes [0:4096] and blocks 0..2 zero [4096:4864]).
//  fillBufferAligned (~42us harness ws re-poison) is an unconditional tax.

#define NPOS 21
#define CIN  128
#define FOUT 256
#define BT   512            // B*T = grid
#define M_TOTAL 10752       // BT*NPOS
#define BN_EPS 1e-3f
#define AROW 136            // A LDS row stride in bf16 (272B: 16B-aligned)
#define PARTS 8
#define CTR    4096         // float-index of arrival counter (own line)
#define FLAGW  4160         // float-index of release flag (own line)
#define SCOFF  4224         // sc[256]
#define BSOFF  4480         // bs[256]
#define WSFRAG 4864         // float offset of W frags in ws (16B aligned)

typedef short v8s __attribute__((ext_vector_type(8)));   // 8 bf16 (4 VGPR)
typedef float v4f __attribute__((ext_vector_type(4)));   // 4 f32 acc

__device__ __forceinline__ uint16_t f2bf_rne(float f) {
    uint32_t u = __builtin_bit_cast(uint32_t, f);
    u += 0x7FFFu + ((u >> 16) & 1u);                     // round-nearest-even
    return (uint16_t)(u >> 16);
}

// 16 blocks x 256: zero partials/ctr/flag/scbs; convert W -> bf16 B-frags.
__global__ __launch_bounds__(256) void k_prep(const float* __restrict__ W,
                                              float* __restrict__ ws)
{
    const int t = threadIdx.x;
    const int b = blockIdx.x;
    ws[b * 256 + t] = 0.0f;                              // zero [0:4096]
    if (b < 3) ws[4096 + b * 256 + t] = 0.0f;            // zero [4096:4864]

    const int q  = b * 256 + t;                          // frag id 0..4095
    const int l  = q & 63;
    const int ks = (q >> 6) & 3;
    const int nt = q >> 8;                               // n-tile 0..15
    const int kb = ks * 32 + (l >> 4) * 8;
    const int col = nt * 16 + (l & 15);
    uint32_t d[4];
    #pragma unroll
    for (int p = 0; p < 4; p++) {
        uint32_t lo = f2bf_rne(W[(size_t)(kb + 2 * p    ) * FOUT + col]);
        uint32_t hi = f2bf_rne(W[(size_t)(kb + 2 * p + 1) * FOUT + col]);
        d[p] = lo | (hi << 16);
    }
    ((uint4*)(ws + WSFRAG))[q] = make_uint4(d[0], d[1], d[2], d[3]);
}

__global__ __launch_bounds__(256, 2) void k_fused(const float* __restrict__ x,
                                                  const float* __restrict__ gamma,
                                                  const float* __restrict__ beta,
                                                  float* __restrict__ y,
                                                  float* ws)
{
    __shared__ uint16_t asB[32 * AROW];    // 8.7 KB bf16 A, pre-shifted
    __shared__ float scL[FOUT];            // partial sums, then scale
    __shared__ float bsL[FOUT];            // partial sumsqs, then bias
    __shared__ unsigned int arriv;

    const int bt = blockIdx.x;
    const int t  = threadIdx.x;

    // ---------- Phase A: stage shifted bf16 A-slab ----------
    for (int i = t; i < 704; i += 256) {   // zero pad rows 21..31
        int r  = 21 + (i >> 6);
        int c2 = (i & 63) << 1;
        *(uint32_t*)&asB[r * AROW + c2] = 0u;
    }
    const float* xin = x + (size_t)bt * (NPOS * CIN);
    for (int i = t; i < NPOS * CIN; i += 256) {
        float v = xin[i];                  // fully coalesced f32 load
        int r = i >> 7;                    // i = r*128 + c
        int c = i & (CIN - 1);
        int s = c % NPOS;
        int n = r + s; if (n >= NPOS) n -= NPOS;
        asB[n * AROW + c] = f2bf_rne(v);   // asB[n][c] == bf16(xs[n][c])
    }

    const int w     = t >> 6;              // wave id -> channel group w*64
    const int l     = t & 63;
    const int row16 = l & 15;
    const int koct  = l >> 4;

    // B fragments: 16 coalesced dwordx4 per lane (1KB/wave-instr)
    const uint4* wsw = (const uint4*)(ws + WSFRAG);
    v8s bfr[4][4];
    #pragma unroll
    for (int nt = 0; nt < 4; nt++)
        #pragma unroll
        for (int ks = 0; ks < 4; ks++) {
            uint4 u = wsw[(((w * 4 + nt) * 4 + ks) << 6) + l];
            bfr[nt][ks] = __builtin_bit_cast(v8s, u);
        }
    __syncthreads();

    // ---------- Phase B: MFMA + per-channel partial sums ----------
    v4f acc[2][4];
    #pragma unroll
    for (int m = 0; m < 2; m++)
        #pragma unroll
        for (int nt = 0; nt < 4; nt++) acc[m][nt] = (v4f){0.f, 0.f, 0.f, 0.f};

    #pragma unroll
    for (int m = 0; m < 2; m++) {
        v8s afr[4];
        #pragma unroll
        for (int ks = 0; ks < 4; ks++)     // ds_read_b128, 16B-aligned
            afr[ks] = *(const v8s*)&asB[(m * 16 + row16) * AROW + ks * 32 + koct * 8];
        #pragma unroll
        for (int ks = 0; ks < 4; ks++)
            #pragma unroll
            for (int nt = 0; nt < 4; nt++)
                acc[m][nt] = __builtin_amdgcn_mfma_f32_16x16x32_bf16(
                                 afr[ks], bfr[nt][ks], acc[m][nt], 0, 0, 0);
    }

    #pragma unroll
    for (int nt = 0; nt < 4; nt++) {
        float s = 0.f, q = 0.f;
        #pragma unroll
        for (int m = 0; m < 2; m++)
            #pragma unroll
            for (int rg = 0; rg < 4; rg++) {
                float v = acc[m][nt][rg];  // pad rows contribute exactly 0
                s += v; q += v * v;
            }
        s += __shfl_xor(s, 16); s += __shfl_xor(s, 32);
        q += __shfl_xor(q, 16); q += __shfl_xor(q, 32);
        if (l < 16) {
            scL[w * 64 + nt * 16 + l] = s;
            bsL[w * 64 + nt * 16 + l] = q;
        }
    }
    __syncthreads();
    {
        float* part = ws + (bt & (PARTS - 1)) * 512;     // 8-way spread
        atomicAdd(part + t, scL[t]);
        atomicAdd(part + 256 + t, bsL[t]);
    }
    __threadfence();                       // release my partial adds
    __syncthreads();

    // ---------- flag barrier: arrivals and release on separate lines ----
    if (t == 0)
        arriv = atomicAdd((unsigned int*)(ws + CTR), 1u);
    __syncthreads();

    if (arriv == (unsigned int)(BT - 1)) {
        // releasing block: alone reads partials, computes + publishes sc/bs
        float s = 0.f, q = 0.f;
        #pragma unroll
        for (int p = 0; p < PARTS; p++) {
            s += __hip_atomic_load(ws + p * 512 + t, __ATOMIC_RELAXED,
                                   __HIP_MEMORY_SCOPE_AGENT);
            q += __hip_atomic_load(ws + p * 512 + 256 + t, __ATOMIC_RELAXED,
                                   __HIP_MEMORY_SCOPE_AGENT);
        }
        const float invM = 1.0f / (float)M_TOTAL;
        float mean = s * invM;
        float var  = fmaf(-mean, mean, q * invM);
        float sc   = rsqrtf(var + BN_EPS) * gamma[t];
        float bs   = beta[t] - mean * sc;
        __hip_atomic_store(ws + SCOFF + t, sc, __ATOMIC_RELAXED,
                           __HIP_MEMORY_SCOPE_AGENT);
        __hip_atomic_store(ws + BSOFF + t, bs, __ATOMIC_RELAXED,
                           __HIP_MEMORY_SCOPE_AGENT);
        scL[t] = sc; bsL[t] = bs;
        __threadfence();
        __syncthreads();                   // all 256 publishes done
        if (t == 0)
            __hip_atomic_store((unsigned int*)(ws + FLAGW), 1u,
                               __ATOMIC_RELEASE, __HIP_MEMORY_SCOPE_AGENT);
    } else {
        if (t == 0) {
            while (__hip_atomic_load((unsigned int*)(ws + FLAGW),
                                     __ATOMIC_ACQUIRE, __HIP_MEMORY_SCOPE_AGENT)
                   == 0u)
                __builtin_amdgcn_s_sleep(16);
        }
        __syncthreads();
        scL[t] = __hip_atomic_load(ws + SCOFF + t, __ATOMIC_RELAXED,
                                   __HIP_MEMORY_SCOPE_AGENT);
        bsL[t] = __hip_atomic_load(ws + BSOFF + t, __ATOMIC_RELAXED,
                                   __HIP_MEMORY_SCOPE_AGENT);
        __syncthreads();
    }

    // ---------- Phase C: normalize in regs, single post-BN y store ----------
    float* yout = y + (size_t)bt * (NPOS * FOUT);
    #pragma unroll
    for (int nt = 0; nt < 4; nt++) {
        const int ch = w * 64 + nt * 16 + row16;
        const float sc = scL[ch];
        const float bs = bsL[ch];
        #pragma unroll
        for (int m = 0; m < 2; m++)
            #pragma unroll
            for (int rg = 0; rg < 4; rg++) {
                int gr = m * 16 + koct * 4 + rg;   // C/D: col=row16, row=koct*4+rg
                if (gr < NPOS)
                    yout[(size_t)gr * FOUT + ch] =
                        fmaxf(fmaf(acc[m][nt][rg], sc, bs), 0.0f);
            }
    }
}

// Template-named symbol kept defined (harness-compat; not launched).
extern "C" __global__ void SpatialShiftConvBlock_71923522339050_kernel() {}

extern "C" void kernel_launch(void* const* d_in, const int* in_sizes, int n_in,
                              void* d_out, int out_size, void* d_ws, size_t ws_size,
                              hipStream_t stream) {
    float* y  = (float*)d_out;             // FLOAT32 output
    float* ws = (float*)d_ws;              // partials | ctr | flag | sc/bs | frags
    k_prep<<<16, 256, 0, stream>>>((const float*)d_in[1], ws);
    k_fused<<<BT, 256, 0, stream>>>((const float*)d_in[0],
                                    (const float*)d_in[3], (const float*)d_in[4],
                                    y, ws);
}

// Round 14
// 91.411 us; speedup vs baseline: 1.6193x; 1.4285x over previous
//
#include <hip/hip_runtime.h>
#include <stdint.h>

// SpatialShiftConvBlock (B=8,T=64,N=21,C=128,F=256):
//   xs[b,t,n,c] = x[b,t,(n - c%21) mod 21, c]       (per-channel circular roll)
//   y  = xs @ W (+ b == 0, and bias cancels in BN anyway)
//   y  = (y - mean)*rsqrt(var + 1e-3)*gamma + beta  (BN training stats over B,T,N)
//   out = relu(y)  (float32 output)
//
// R42: back to the 3-kernel R37 structure (best passing: 91.4us). The fused
// grid-barrier design cost 50-60us of structural dead time across three
// protocol variants (R38 68us / R40 95us / R41 75us k_fused @ <2% VALUBusy):
// tail-block gating + cross-XCD release propagation; the 33MB y round-trip it
// saves is worth only ~5-9us. Dropped for good.
// Improvements over R37:
//  - k_prep: 16 blocks, ONE frag/thread (R37: 4 blocks, 4 frags) -> ~3-4us.
//  - k_conv: grid 1024 = (bt, F-half). Channel-split (R36 lesson: per-wave
//    frag bytes scale with channels, so total traffic constant) -> B-frags
//    16KB/block, VGPR ~75, LDS ~10KB -> 4 blocks/CU = 16 waves/CU (2x R37
//    TLP for the latency-bound staging). x HBM doubles to 11MB (+1.7us).
//  - k_bnapply unchanged (~9us, near 22MB streaming floor).
// Frag maps (HW-verified m89): A: row=l&15,k=(l>>4)*8+j; B: col=l&15 same k;
// C/D: col=l&15,row=(l>>4)*4+reg.
// ws floats: [0:256] ch sums, [256:512] ch sumsqs, [1024:17408] bf16 W frags.
// fillBufferAligned (~42us harness ws re-poison) is an unconditional tax.

#define NPOS 21
#define CIN  128
#define FOUT 256
#define BT   512            // B*T
#define M_TOTAL 10752       // BT*NPOS
#define BN_EPS 1e-3f
#define AROW 136            // A LDS row stride in bf16 (272B: 16B-aligned)
#define WSFRAG 1024         // float offset of W frags in ws

typedef short v8s __attribute__((ext_vector_type(8)));   // 8 bf16 (4 VGPR)
typedef float v4f __attribute__((ext_vector_type(4)));   // 4 f32 acc

__device__ __forceinline__ uint16_t f2bf_rne(float f) {
    uint32_t u = __builtin_bit_cast(uint32_t, f);
    u += 0x7FFFu + ((u >> 16) & 1u);                     // round-nearest-even
    return (uint16_t)(u >> 16);
}

// 16 blocks x 256: zero stats; convert W -> bf16 B-frags (1 frag/thread).
__global__ __launch_bounds__(256) void k_prep(const float* __restrict__ W,
                                              float* __restrict__ ws)
{
    const int t = threadIdx.x;
    const int b = blockIdx.x;
    if (b < 2) ws[b * 256 + t] = 0.0f;                   // zero [0:512]

    const int q  = b * 256 + t;                          // frag id 0..4095
    const int l  = q & 63;
    const int ks = (q >> 6) & 3;
    const int nt = q >> 8;                               // n-tile 0..15
    const int kb = ks * 32 + (l >> 4) * 8;
    const int col = nt * 16 + (l & 15);
    uint32_t d[4];
    #pragma unroll
    for (int p = 0; p < 4; p++) {
        uint32_t lo = f2bf_rne(W[(size_t)(kb + 2 * p    ) * FOUT + col]);
        uint32_t hi = f2bf_rne(W[(size_t)(kb + 2 * p + 1) * FOUT + col]);
        d[p] = lo | (hi << 16);
    }
    ((uint4*)(ws + WSFRAG))[q] = make_uint4(d[0], d[1], d[2], d[3]);
}

// grid 1024 = (bt, F-half). Block: stage shifted bf16 A slab; wave w covers
// 32 channels (2 n-tiles) x all 21 rows (2 m-tiles); 16 MFMAs/wave.
__global__ __launch_bounds__(256) void k_conv(const float* __restrict__ x,
                                              float* __restrict__ y,
                                              float* ws)
{
    __shared__ uint16_t asB[32 * AROW];    // 8.7 KB bf16 A, pre-shifted
    __shared__ float scL[128], sqL[128];   // block's 128-channel partial sums

    const int bt = blockIdx.x >> 1;
    const int fh = blockIdx.x & 1;         // F-half
    const int t  = threadIdx.x;

    // ---------- stage shifted bf16 A-slab ----------
    for (int i = t; i < 704; i += 256) {   // zero pad rows 21..31
        int r  = 21 + (i >> 6);
        int c2 = (i & 63) << 1;
        *(uint32_t*)&asB[r * AROW + c2] = 0u;
    }
    const float* xin = x + (size_t)bt * (NPOS * CIN);
    for (int i = t; i < NPOS * CIN; i += 256) {
        float v = xin[i];                  // fully coalesced f32 load
        int r = i >> 7;                    // i = r*128 + c
        int c = i & (CIN - 1);
        int s = c % NPOS;
        int n = r + s; if (n >= NPOS) n -= NPOS;
        asB[n * AROW + c] = f2bf_rne(v);   // asB[n][c] == bf16(xs[n][c])
    }

    const int w     = t >> 6;              // wave id -> 32-channel group
    const int l     = t & 63;
    const int row16 = l & 15;
    const int koct  = l >> 4;

    // B fragments: 8 coalesced dwordx4 per lane (1KB/wave-instr)
    const uint4* wsw = (const uint4*)(ws + WSFRAG);
    v8s bfr[2][4];
    #pragma unroll
    for (int nt = 0; nt < 2; nt++) {
        const int ntg = fh * 8 + w * 2 + nt;             // global n-tile
        #pragma unroll
        for (int ks = 0; ks < 4; ks++) {
            uint4 u = wsw[(((ntg << 2) + ks) << 6) + l];
            bfr[nt][ks] = __builtin_bit_cast(v8s, u);
        }
    }
    __syncthreads();

    // ---------- MFMA ----------
    v4f acc[2][2];
    #pragma unroll
    for (int m = 0; m < 2; m++)
        #pragma unroll
        for (int nt = 0; nt < 2; nt++) acc[m][nt] = (v4f){0.f, 0.f, 0.f, 0.f};

    #pragma unroll
    for (int m = 0; m < 2; m++) {
        v8s afr[4];
        #pragma unroll
        for (int ks = 0; ks < 4; ks++)     // ds_read_b128, 16B-aligned
            afr[ks] = *(const v8s*)&asB[(m * 16 + row16) * AROW + ks * 32 + koct * 8];
        #pragma unroll
        for (int ks = 0; ks < 4; ks++)
            #pragma unroll
            for (int nt = 0; nt < 2; nt++)
                acc[m][nt] = __builtin_amdgcn_mfma_f32_16x16x32_bf16(
                                 afr[ks], bfr[nt][ks], acc[m][nt], 0, 0, 0);
    }

    // ---------- y store (pre-norm) + per-channel sums ----------
    float* yout = y + (size_t)bt * (NPOS * FOUT) + fh * 128 + w * 32;
    #pragma unroll
    for (int nt = 0; nt < 2; nt++) {
        float s = 0.f, q = 0.f;
        #pragma unroll
        for (int m = 0; m < 2; m++)
            #pragma unroll
            for (int rg = 0; rg < 4; rg++) {
                float v = acc[m][nt][rg];  // pad rows contribute exactly 0
                s += v; q += v * v;
                int gr = m * 16 + koct * 4 + rg;   // C/D: col=row16, row=koct*4+rg
                if (gr < NPOS)
                    yout[(size_t)gr * FOUT + nt * 16 + row16] = v;
            }
        s += __shfl_xor(s, 16); s += __shfl_xor(s, 32);
        q += __shfl_xor(q, 16); q += __shfl_xor(q, 32);
        if (l < 16) {
            scL[w * 32 + nt * 16 + l] = s;
            sqL[w * 32 + nt * 16 + l] = q;
        }
    }
    __syncthreads();

    // 256 atomics/block; each stats address gets 512 adds over the grid
    if (t < 128) atomicAdd(ws + fh * 128 + t, scL[t]);
    else         atomicAdd(ws + 256 + fh * 128 + (t - 128), sqL[t - 128]);
}

#define BN_BLOCKS 1344      // 1344 * 512 float4 = 688128 = 10752*256/4 exactly

__global__ __launch_bounds__(256) void k_bnapply(float* __restrict__ y,
                                                 const float* __restrict__ ws,
                                                 const float* __restrict__ gamma,
                                                 const float* __restrict__ beta)
{
    const int t  = threadIdx.x;
    const int fb = (t & 63) << 2;          // this thread's fixed channel quad
    const float4 sm = *(const float4*)(ws + fb);
    const float4 sq = *(const float4*)(ws + FOUT + fb);
    const float4 gm = *(const float4*)(gamma + fb);
    const float4 be = *(const float4*)(beta + fb);
    const float invM = 1.0f / (float)M_TOTAL;

    float sc[4], bs[4];
    {
        float m0 = sm.x * invM, m1 = sm.y * invM, m2 = sm.z * invM, m3 = sm.w * invM;
        float v0 = fmaf(-m0, m0, sq.x * invM);
        float v1 = fmaf(-m1, m1, sq.y * invM);
        float v2 = fmaf(-m2, m2, sq.z * invM);
        float v3 = fmaf(-m3, m3, sq.w * invM);
        sc[0] = rsqrtf(v0 + BN_EPS) * gm.x;  bs[0] = be.x - m0 * sc[0];
        sc[1] = rsqrtf(v1 + BN_EPS) * gm.y;  bs[1] = be.y - m1 * sc[1];
        sc[2] = rsqrtf(v2 + BN_EPS) * gm.z;  bs[2] = be.z - m2 * sc[2];
        sc[3] = rsqrtf(v3 + BN_EPS) * gm.w;  bs[3] = be.w - m3 * sc[3];
    }

    float4* y4 = (float4*)y;
    #pragma unroll
    for (int it = 0; it < 2; it++) {
        int g = blockIdx.x * 512 + it * 256 + t;   // g%64 == t&63 -> quad matches fb
        float4 v = y4[g];
        v.x = fmaxf(fmaf(v.x, sc[0], bs[0]), 0.0f);
        v.y = fmaxf(fmaf(v.y, sc[1], bs[1]), 0.0f);
        v.z = fmaxf(fmaf(v.z, sc[2], bs[2]), 0.0f);
        v.w = fmaxf(fmaf(v.w, sc[3], bs[3]), 0.0f);
        y4[g] = v;
    }
}

// Template-named symbol kept defined (harness-compat; not launched).
extern "C" __global__ void SpatialShiftConvBlock_71923522339050_kernel() {}

extern "C" void kernel_launch(void* const* d_in, const int* in_sizes, int n_in,
                              void* d_out, int out_size, void* d_ws, size_t ws_size,
                              hipStream_t stream) {
    float* y  = (float*)d_out;             // FLOAT32 output
    float* ws = (float*)d_ws;              // sums | sumsqs | bf16 W frags
    k_prep<<<16, 256, 0, stream>>>((const float*)d_in[1], ws);
    k_conv<<<2 * BT, 256, 0, stream>>>((const float*)d_in[0], y, ws);
    k_bnapply<<<BN_BLOCKS, 256, 0, stream>>>(y, ws,
                                             (const float*)d_in[3], (const float*)d_in[4]);
}

// Round 15
// 82.493 us; speedup vs baseline: 1.7943x; 1.1081x over previous
//
#include <hip/hip_runtime.h>
#include <stdint.h>

// SpatialShiftConvBlock (B=8,T=64,N=21,C=128,F=256):
//   xs[b,t,n,c] = x[b,t,(n - c%21) mod 21, c]       (per-channel circular roll)
//   y  = xs @ W (+ b == 0, and bias cancels in BN anyway)
//   y  = (y - mean)*rsqrt(var + 1e-3)*gamma + beta  (BN training stats over B,T,N)
//   out = relu(y)  (float32 output)
//
// R43: atomic-funnel fix. Budget analysis (totals minus measured fill/bn/prep
// across R35/R37/R40/R42) shows k_conv ~30us in both R37 and R42 shapes while
// its compute critical path is ~1-2us/block with one grid round. The common
// serializer: every conv ends with 512 blocks x 512 atomicAdds to the SAME
// 512 addresses (~32 TCC lines -> ~8K serialized RMWs/line ~= 7-14us tail).
// Fix (R39's idea, never unconfounded): 8-way partial spread, part=(bt&7).
//  - k_conv: R37's proven full-F 512-block body (R42's F-split reverted: it
//    duplicated staging for zero gain); atomics -> ws+(bt&7)*512 (64/addr).
//  - k_prep: 16 blocks, zero the 4096-float partial region, convert W->bf16
//    B-frags (1 frag/thread) at ws+4096.
//  - k_bnapply: sums 8 partials (16 L2-hot float4 loads), then streams y.
// Frag maps (HW-verified m89): A: row=l&15,k=(l>>4)*8+j; B: col=l&15 same k;
// C/D: col=l&15,row=(l>>4)*4+reg.
// ws floats: [0:4096] 8x{256 sums,256 sumsqs}; [4096:20480] bf16 W frags.
// fillBufferAligned (~42us harness ws re-poison) is an unconditional tax.

#define NPOS 21
#define CIN  128
#define FOUT 256
#define BT   512            // B*T
#define M_TOTAL 10752       // BT*NPOS
#define BN_EPS 1e-3f
#define AROW 136            // A LDS row stride in bf16 (272B: 16B-aligned)
#define PARTS 8
#define WSFRAG 4096         // float offset of W frags in ws (16KB aligned)

typedef short v8s __attribute__((ext_vector_type(8)));   // 8 bf16 (4 VGPR)
typedef float v4f __attribute__((ext_vector_type(4)));   // 4 f32 acc

__device__ __forceinline__ uint16_t f2bf_rne(float f) {
    uint32_t u = __builtin_bit_cast(uint32_t, f);
    u += 0x7FFFu + ((u >> 16) & 1u);                     // round-nearest-even
    return (uint16_t)(u >> 16);
}

// 16 blocks x 256: zero the 8 partial arrays; convert W -> bf16 B-frags.
__global__ __launch_bounds__(256) void k_prep(const float* __restrict__ W,
                                              float* __restrict__ ws)
{
    const int t = threadIdx.x;
    const int b = blockIdx.x;
    ws[b * 256 + t] = 0.0f;                              // zero [0:4096]

    const int q  = b * 256 + t;                          // frag id 0..4095
    const int l  = q & 63;
    const int ks = (q >> 6) & 3;
    const int nt = q >> 8;                               // n-tile 0..15
    const int kb = ks * 32 + (l >> 4) * 8;
    const int col = nt * 16 + (l & 15);
    uint32_t d[4];
    #pragma unroll
    for (int p = 0; p < 4; p++) {
        uint32_t lo = f2bf_rne(W[(size_t)(kb + 2 * p    ) * FOUT + col]);
        uint32_t hi = f2bf_rne(W[(size_t)(kb + 2 * p + 1) * FOUT + col]);
        d[p] = lo | (hi << 16);
    }
    ((uint4*)(ws + WSFRAG))[q] = make_uint4(d[0], d[1], d[2], d[3]);
}

// 512 blocks (one per bt-slab), full F per block; wave w: 64 channels,
// 2 m-tiles x 4 n-tiles x 4 k-steps = 32 MFMAs.
__global__ __launch_bounds__(256) void k_conv(const float* __restrict__ x,
                                              float* __restrict__ y,
                                              float* ws)
{
    __shared__ uint16_t asB[32 * AROW];    // 8.7 KB bf16 A, pre-shifted
    __shared__ float sumL[FOUT], sqL[FOUT];

    const int bt = blockIdx.x;
    const int t  = threadIdx.x;

    // ---------- stage shifted bf16 A-slab ----------
    for (int i = t; i < 704; i += 256) {   // zero pad rows 21..31
        int r  = 21 + (i >> 6);
        int c2 = (i & 63) << 1;
        *(uint32_t*)&asB[r * AROW + c2] = 0u;
    }
    const float* xin = x + (size_t)bt * (NPOS * CIN);
    for (int i = t; i < NPOS * CIN; i += 256) {
        float v = xin[i];                  // fully coalesced f32 load
        int r = i >> 7;                    // i = r*128 + c
        int c = i & (CIN - 1);
        int s = c % NPOS;
        int n = r + s; if (n >= NPOS) n -= NPOS;
        asB[n * AROW + c] = f2bf_rne(v);   // asB[n][c] == bf16(xs[n][c])
    }

    const int w     = t >> 6;              // wave id -> channel group w*64
    const int l     = t & 63;
    const int row16 = l & 15;
    const int koct  = l >> 4;

    // B fragments: 16 coalesced dwordx4 per lane (1KB/wave-instr)
    const uint4* wsw = (const uint4*)(ws + WSFRAG);
    v8s bfr[4][4];
    #pragma unroll
    for (int nt = 0; nt < 4; nt++)
        #pragma unroll
        for (int ks = 0; ks < 4; ks++) {
            uint4 u = wsw[(((w * 4 + nt) * 4 + ks) << 6) + l];
            bfr[nt][ks] = __builtin_bit_cast(v8s, u);
        }
    __syncthreads();

    // ---------- MFMA ----------
    v4f acc[2][4];
    #pragma unroll
    for (int m = 0; m < 2; m++)
        #pragma unroll
        for (int nt = 0; nt < 4; nt++) acc[m][nt] = (v4f){0.f, 0.f, 0.f, 0.f};

    #pragma unroll
    for (int m = 0; m < 2; m++) {
        v8s afr[4];
        #pragma unroll
        for (int ks = 0; ks < 4; ks++)     // ds_read_b128, 16B-aligned
            afr[ks] = *(const v8s*)&asB[(m * 16 + row16) * AROW + ks * 32 + koct * 8];
        #pragma unroll
        for (int ks = 0; ks < 4; ks++)
            #pragma unroll
            for (int nt = 0; nt < 4; nt++)
                acc[m][nt] = __builtin_amdgcn_mfma_f32_16x16x32_bf16(
                                 afr[ks], bfr[nt][ks], acc[m][nt], 0, 0, 0);
    }

    // ---------- y store (pre-norm) + per-channel sums ----------
    float* yout = y + (size_t)bt * (NPOS * FOUT) + w * 64;
    #pragma unroll
    for (int nt = 0; nt < 4; nt++) {
        float s = 0.f, q = 0.f;
        #pragma unroll
        for (int m = 0; m < 2; m++)
            #pragma unroll
            for (int rg = 0; rg < 4; rg++) {
                float v = acc[m][nt][rg];  // pad rows contribute exactly 0
                s += v; q += v * v;
                int gr = m * 16 + koct * 4 + rg;   // C/D: col=row16, row=koct*4+rg
                if (gr < NPOS)
                    yout[(size_t)gr * FOUT + nt * 16 + row16] = v;
            }
        s += __shfl_xor(s, 16); s += __shfl_xor(s, 32);
        q += __shfl_xor(q, 16); q += __shfl_xor(q, 32);
        if (l < 16) {
            sumL[w * 64 + nt * 16 + l] = s;
            sqL [w * 64 + nt * 16 + l] = q;
        }
    }
    __syncthreads();

    // 8-way spread: 64 adds/address over 256 lines (was 512/addr on 32 lines)
    float* part = ws + (bt & (PARTS - 1)) * 512;
    atomicAdd(part + t, sumL[t]);
    atomicAdd(part + 256 + t, sqL[t]);
}

#define BN_BLOCKS 1344      // 1344 * 512 float4 = 688128 = 10752*256/4 exactly

__global__ __launch_bounds__(256) void k_bnapply(float* __restrict__ y,
                                                 const float* __restrict__ ws,
                                                 const float* __restrict__ gamma,
                                                 const float* __restrict__ beta)
{
    const int t  = threadIdx.x;
    const int fb = (t & 63) << 2;          // this thread's fixed channel quad
    float4 sm = make_float4(0.f, 0.f, 0.f, 0.f);
    float4 sq = make_float4(0.f, 0.f, 0.f, 0.f);
    #pragma unroll
    for (int p = 0; p < PARTS; p++) {      // L2-hot partial arrays
        float4 a = *(const float4*)(ws + p * 512 + fb);
        float4 b = *(const float4*)(ws + p * 512 + 256 + fb);
        sm.x += a.x; sm.y += a.y; sm.z += a.z; sm.w += a.w;
        sq.x += b.x; sq.y += b.y; sq.z += b.z; sq.w += b.w;
    }
    const float4 gm = *(const float4*)(gamma + fb);
    const float4 be = *(const float4*)(beta + fb);
    const float invM = 1.0f / (float)M_TOTAL;

    float sc[4], bs[4];
    {
        float m0 = sm.x * invM, m1 = sm.y * invM, m2 = sm.z * invM, m3 = sm.w * invM;
        float v0 = fmaf(-m0, m0, sq.x * invM);
        float v1 = fmaf(-m1, m1, sq.y * invM);
        float v2 = fmaf(-m2, m2, sq.z * invM);
        float v3 = fmaf(-m3, m3, sq.w * invM);
        sc[0] = rsqrtf(v0 + BN_EPS) * gm.x;  bs[0] = be.x - m0 * sc[0];
        sc[1] = rsqrtf(v1 + BN_EPS) * gm.y;  bs[1] = be.y - m1 * sc[1];
        sc[2] = rsqrtf(v2 + BN_EPS) * gm.z;  bs[2] = be.z - m2 * sc[2];
        sc[3] = rsqrtf(v3 + BN_EPS) * gm.w;  bs[3] = be.w - m3 * sc[3];
    }

    float4* y4 = (float4*)y;
    #pragma unroll
    for (int it = 0; it < 2; it++) {
        int g = blockIdx.x * 512 + it * 256 + t;   // g%64 == t&63 -> quad matches fb
        float4 v = y4[g];
        v.x = fmaxf(fmaf(v.x, sc[0], bs[0]), 0.0f);
        v.y = fmaxf(fmaf(v.y, sc[1], bs[1]), 0.0f);
        v.z = fmaxf(fmaf(v.z, sc[2], bs[2]), 0.0f);
        v.w = fmaxf(fmaf(v.w, sc[3], bs[3]), 0.0f);
        y4[g] = v;
    }
}

// Template-named symbol kept defined (harness-compat; not launched).
extern "C" __global__ void SpatialShiftConvBlock_71923522339050_kernel() {}

extern "C" void kernel_launch(void* const* d_in, const int* in_sizes, int n_in,
                              void* d_out, int out_size, void* d_ws, size_t ws_size,
                              hipStream_t stream) {
    float* y  = (float*)d_out;             // FLOAT32 output
    float* ws = (float*)d_ws;              // 8x partials | bf16 W frags
    k_prep<<<16, 256, 0, stream>>>((const float*)d_in[1], ws);
    k_conv<<<BT, 256, 0, stream>>>((const float*)d_in[0], y, ws);
    k_bnapply<<<BN_BLOCKS, 256, 0, stream>>>(y, ws,
                                             (const float*)d_in[3], (const float*)d_in[4]);
}

// Round 16
// 79.114 us; speedup vs baseline: 1.8710x; 1.0427x over previous
//
#include <hip/hip_runtime.h>
#include <stdint.h>

// SpatialShiftConvBlock (B=8,T=64,N=21,C=128,F=256):
//   xs[b,t,n,c] = x[b,t,(n - c%21) mod 21, c]       (per-channel circular roll)
//   y  = xs @ W (+ b == 0, and bias cancels in BN anyway)
//   y  = (y - mean)*rsqrt(var + 1e-3)*gamma + beta  (BN training stats over B,T,N)
//   out = relu(y)  (float32 output)
//
// R44 = R43 (82.5us, best) + three width/contention cuts:
//  1. Pre-norm y stored as BF16 in ws (5.5MB, was 11MB f32 in d_out): conv
//     write and bn read halve. Precision: extra bf16 rounding of y adds
//     ~|y|max*2^-9 ~= 0.01 abs; R43 absmax 0.031, threshold 0.103 -> safe.
//  2. Stats partial spread PARTS 8 -> 32 (16 adds/address; R43's 8-way spread
//     was worth ~9us vs the 512/addr funnel).
//  3. k_bnapply: 672 blocks, sc/bs computed once per block into LDS from
//     COALESCED partial reads (ws[p*512+t], consecutive t), main loop =
//     1 uint4 bf16 load + 4 ds_read_b128 + 2 float4 stores per thread x2.
// Frag maps (HW-verified m89): A: row=l&15,k=(l>>4)*8+j; B: col=l&15 same k;
// C/D: col=l&15,row=(l>>4)*4+reg.
// ws floats: [0:16384] 32x{256 sums,256 sumsqs}; [16384:32768] bf16 W frags;
// [32768:...] bf16 pre-norm y [10752][256] (5.5MB).
// fillBufferAligned (~41us harness ws re-poison) is an unconditional tax.

#define NPOS 21
#define CIN  128
#define FOUT 256
#define BT   512            // B*T
#define M_TOTAL 10752       // BT*NPOS
#define BN_EPS 1e-3f
#define AROW 136            // A LDS row stride in bf16 (272B: 16B-aligned)
#define PARTS 32
#define WSFRAG 16384        // float offset of W frags
#define WSY    32768        // float offset of bf16 pre-norm y

typedef short v8s __attribute__((ext_vector_type(8)));   // 8 bf16 (4 VGPR)
typedef float v4f __attribute__((ext_vector_type(4)));   // 4 f32 acc

__device__ __forceinline__ uint16_t f2bf_rne(float f) {
    uint32_t u = __builtin_bit_cast(uint32_t, f);
    u += 0x7FFFu + ((u >> 16) & 1u);                     // round-nearest-even
    return (uint16_t)(u >> 16);
}
__device__ __forceinline__ float bf2f_lo(uint32_t d) {
    return __builtin_bit_cast(float, d << 16);
}
__device__ __forceinline__ float bf2f_hi(uint32_t d) {
    return __builtin_bit_cast(float, d & 0xFFFF0000u);
}

// 16 blocks x 256: zero the 32 partial arrays (64KB); convert W -> bf16 frags.
__global__ __launch_bounds__(256) void k_prep(const float* __restrict__ W,
                                              float* __restrict__ ws)
{
    const int t = threadIdx.x;
    const int b = blockIdx.x;
    ((float4*)ws)[b * 256 + t] = make_float4(0.f, 0.f, 0.f, 0.f);  // [0:16384]

    const int q  = b * 256 + t;                          // frag id 0..4095
    const int l  = q & 63;
    const int ks = (q >> 6) & 3;
    const int nt = q >> 8;                               // n-tile 0..15
    const int kb = ks * 32 + (l >> 4) * 8;
    const int col = nt * 16 + (l & 15);
    uint32_t d[4];
    #pragma unroll
    for (int p = 0; p < 4; p++) {
        uint32_t lo = f2bf_rne(W[(size_t)(kb + 2 * p    ) * FOUT + col]);
        uint32_t hi = f2bf_rne(W[(size_t)(kb + 2 * p + 1) * FOUT + col]);
        d[p] = lo | (hi << 16);
    }
    ((uint4*)(ws + WSFRAG))[q] = make_uint4(d[0], d[1], d[2], d[3]);
}

// 512 blocks (one per bt-slab), full F per block; wave w: 64 channels,
// 2 m-tiles x 4 n-tiles x 4 k-steps = 32 MFMAs. Pre-norm y stored bf16 in ws.
__global__ __launch_bounds__(256) void k_conv(const float* __restrict__ x,
                                              float* ws)
{
    __shared__ uint16_t asB[32 * AROW];    // 8.7 KB bf16 A, pre-shifted
    __shared__ float sumL[FOUT], sqL[FOUT];

    const int bt = blockIdx.x;
    const int t  = threadIdx.x;

    // ---------- stage shifted bf16 A-slab ----------
    for (int i = t; i < 704; i += 256) {   // zero pad rows 21..31
        int r  = 21 + (i >> 6);
        int c2 = (i & 63) << 1;
        *(uint32_t*)&asB[r * AROW + c2] = 0u;
    }
    const float* xin = x + (size_t)bt * (NPOS * CIN);
    for (int i = t; i < NPOS * CIN; i += 256) {
        float v = xin[i];                  // fully coalesced f32 load
        int r = i >> 7;                    // i = r*128 + c
        int c = i & (CIN - 1);
        int s = c % NPOS;
        int n = r + s; if (n >= NPOS) n -= NPOS;
        asB[n * AROW + c] = f2bf_rne(v);   // asB[n][c] == bf16(xs[n][c])
    }

    const int w     = t >> 6;              // wave id -> channel group w*64
    const int l     = t & 63;
    const int row16 = l & 15;
    const int koct  = l >> 4;

    // B fragments: 16 coalesced dwordx4 per lane (1KB/wave-instr)
    const uint4* wsw = (const uint4*)(ws + WSFRAG);
    v8s bfr[4][4];
    #pragma unroll
    for (int nt = 0; nt < 4; nt++)
        #pragma unroll
        for (int ks = 0; ks < 4; ks++) {
            uint4 u = wsw[(((w * 4 + nt) * 4 + ks) << 6) + l];
            bfr[nt][ks] = __builtin_bit_cast(v8s, u);
        }
    __syncthreads();

    // ---------- MFMA ----------
    v4f acc[2][4];
    #pragma unroll
    for (int m = 0; m < 2; m++)
        #pragma unroll
        for (int nt = 0; nt < 4; nt++) acc[m][nt] = (v4f){0.f, 0.f, 0.f, 0.f};

    #pragma unroll
    for (int m = 0; m < 2; m++) {
        v8s afr[4];
        #pragma unroll
        for (int ks = 0; ks < 4; ks++)     // ds_read_b128, 16B-aligned
            afr[ks] = *(const v8s*)&asB[(m * 16 + row16) * AROW + ks * 32 + koct * 8];
        #pragma unroll
        for (int ks = 0; ks < 4; ks++)
            #pragma unroll
            for (int nt = 0; nt < 4; nt++)
                acc[m][nt] = __builtin_amdgcn_mfma_f32_16x16x32_bf16(
                                 afr[ks], bfr[nt][ks], acc[m][nt], 0, 0, 0);
    }

    // ---------- bf16 y store (pre-norm) + per-channel sums ----------
    uint16_t* yws = (uint16_t*)(ws + WSY);
    uint16_t* yout = yws + (size_t)bt * (NPOS * FOUT) + w * 64;
    #pragma unroll
    for (int nt = 0; nt < 4; nt++) {
        float s = 0.f, q = 0.f;
        #pragma unroll
        for (int m = 0; m < 2; m++)
            #pragma unroll
            for (int rg = 0; rg < 4; rg++) {
                float v = acc[m][nt][rg];  // pad rows contribute exactly 0
                s += v; q += v * v;
                int gr = m * 16 + koct * 4 + rg;   // C/D: col=row16, row=koct*4+rg
                if (gr < NPOS)
                    yout[(size_t)gr * FOUT + nt * 16 + row16] = f2bf_rne(v);
            }
        s += __shfl_xor(s, 16); s += __shfl_xor(s, 32);
        q += __shfl_xor(q, 16); q += __shfl_xor(q, 32);
        if (l < 16) {
            sumL[w * 64 + nt * 16 + l] = s;
            sqL [w * 64 + nt * 16 + l] = q;
        }
    }
    __syncthreads();

    // 32-way spread: 16 adds/address
    float* part = ws + (bt & (PARTS - 1)) * 512;
    atomicAdd(part + t, sumL[t]);
    atomicAdd(part + 256 + t, sqL[t]);
}

// 672 blocks: each handles 16 m-rows. sc/bs once per block into LDS
// (coalesced partial reads), then 2 iterations of bf16->f32 normalize.
__global__ __launch_bounds__(256) void k_bnapply(const float* __restrict__ ws,
                                                 const float* __restrict__ gamma,
                                                 const float* __restrict__ beta,
                                                 float* __restrict__ y)
{
    __shared__ float scL[FOUT], bsL[FOUT];
    const int t = threadIdx.x;

    {   // channel t: sum the 32 partials (coalesced: consecutive t)
        float s = 0.f, q = 0.f;
        #pragma unroll
        for (int p = 0; p < PARTS; p++) {
            s += ws[p * 512 + t];
            q += ws[p * 512 + 256 + t];
        }
        const float invM = 1.0f / (float)M_TOTAL;
        float mean = s * invM;
        float var  = fmaf(-mean, mean, q * invM);
        float sc   = rsqrtf(var + BN_EPS) * gamma[t];
        scL[t] = sc;
        bsL[t] = beta[t] - mean * sc;
    }
    __syncthreads();

    const int fb = (t & 31) << 3;          // this thread's 8-channel base
    const uint16_t* yws = (const uint16_t*)(ws + WSY);
    const float4 sc0 = *(const float4*)&scL[fb];
    const float4 sc1 = *(const float4*)&scL[fb + 4];
    const float4 bs0 = *(const float4*)&bsL[fb];
    const float4 bs1 = *(const float4*)&bsL[fb + 4];

    #pragma unroll
    for (int it = 0; it < 2; it++) {
        int m = blockIdx.x * 16 + it * 8 + (t >> 5);
        uint4 u = *(const uint4*)(yws + (size_t)m * FOUT + fb);
        float4 o0, o1;
        o0.x = fmaxf(fmaf(bf2f_lo(u.x), sc0.x, bs0.x), 0.0f);
        o0.y = fmaxf(fmaf(bf2f_hi(u.x), sc0.y, bs0.y), 0.0f);
        o0.z = fmaxf(fmaf(bf2f_lo(u.y), sc0.z, bs0.z), 0.0f);
        o0.w = fmaxf(fmaf(bf2f_hi(u.y), sc0.w, bs0.w), 0.0f);
        o1.x = fmaxf(fmaf(bf2f_lo(u.z), sc1.x, bs1.x), 0.0f);
        o1.y = fmaxf(fmaf(bf2f_hi(u.z), sc1.y, bs1.y), 0.0f);
        o1.z = fmaxf(fmaf(bf2f_lo(u.w), sc1.z, bs1.z), 0.0f);
        o1.w = fmaxf(fmaf(bf2f_hi(u.w), sc1.w, bs1.w), 0.0f);
        float* yo = y + (size_t)m * FOUT + fb;
        *(float4*)yo       = o0;
        *(float4*)(yo + 4) = o1;
    }
}

// Template-named symbol kept defined (harness-compat; not launched).
extern "C" __global__ void SpatialShiftConvBlock_71923522339050_kernel() {}

extern "C" void kernel_launch(void* const* d_in, const int* in_sizes, int n_in,
                              void* d_out, int out_size, void* d_ws, size_t ws_size,
                              hipStream_t stream) {
    float* y  = (float*)d_out;             // FLOAT32 output
    float* ws = (float*)d_ws;              // 32x partials | W frags | bf16 y
    k_prep<<<16, 256, 0, stream>>>((const float*)d_in[1], ws);
    k_conv<<<BT, 256, 0, stream>>>((const float*)d_in[0], ws);
    k_bnapply<<<672, 256, 0, stream>>>(ws, (const float*)d_in[3],
                                       (const float*)d_in[4], y);
}

// Round 17
// 77.270 us; speedup vs baseline: 1.9156x; 1.0239x over previous
//
#include <hip/hip_runtime.h>
#include <stdint.h>

// SpatialShiftConvBlock (B=8,T=64,N=21,C=128,F=256):
//   xs[b,t,n,c] = x[b,t,(n - c%21) mod 21, c]       (per-channel circular roll)
//   y  = xs @ W (+ b == 0, and bias cancels in BN anyway)
//   y  = (y - mean)*rsqrt(var + 1e-3)*gamma + beta  (BN training stats over B,T,N)
//   out = relu(y)  (float32 output)
//
// R45 = R44 (79.1us, best) + k_conv issue-count surgery:
//  1. float4 staging: 672 dwordx4/block (was 2688 dword) -> 4x fewer VMEM
//     issues + address calcs. Shift applied per element of the quad via
//     incremental s=(c%21) (wraps inside a quad handled); LDS stores stay
//     scalar u16 (never the cost).
//  2. B-frag dwordx4 loads HOISTED before staging so their L2 latency
//     overlaps the HBM staging drain (were issued after, stacking).
//  Everything else identical to R44 (k_prep 16-blk 1-frag/thread; bf16
//  pre-norm y in ws; PARTS=32 atomic spread; k_bnapply 672-blk).
// Frag maps (HW-verified m89): A: row=l&15,k=(l>>4)*8+j; B: col=l&15 same k;
// C/D: col=l&15,row=(l>>4)*4+reg.
// ws floats: [0:16384] 32x{256 sums,256 sumsqs}; [16384:32768] bf16 W frags;
// [32768:...] bf16 pre-norm y [10752][256] (5.5MB).
// fillBufferAligned (~41us harness ws re-poison) is an unconditional tax.

#define NPOS 21
#define CIN  128
#define FOUT 256
#define BT   512            // B*T
#define M_TOTAL 10752       // BT*NPOS
#define BN_EPS 1e-3f
#define AROW 136            // A LDS row stride in bf16 (272B: 16B-aligned)
#define PARTS 32
#define WSFRAG 16384        // float offset of W frags
#define WSY    32768        // float offset of bf16 pre-norm y

typedef short v8s __attribute__((ext_vector_type(8)));   // 8 bf16 (4 VGPR)
typedef float v4f __attribute__((ext_vector_type(4)));   // 4 f32 acc

__device__ __forceinline__ uint16_t f2bf_rne(float f) {
    uint32_t u = __builtin_bit_cast(uint32_t, f);
    u += 0x7FFFu + ((u >> 16) & 1u);                     // round-nearest-even
    return (uint16_t)(u >> 16);
}
__device__ __forceinline__ float bf2f_lo(uint32_t d) {
    return __builtin_bit_cast(float, d << 16);
}
__device__ __forceinline__ float bf2f_hi(uint32_t d) {
    return __builtin_bit_cast(float, d & 0xFFFF0000u);
}

// 16 blocks x 256: zero the 32 partial arrays (64KB); convert W -> bf16 frags.
__global__ __launch_bounds__(256) void k_prep(const float* __restrict__ W,
                                              float* __restrict__ ws)
{
    const int t = threadIdx.x;
    const int b = blockIdx.x;
    ((float4*)ws)[b * 256 + t] = make_float4(0.f, 0.f, 0.f, 0.f);  // [0:16384]

    const int q  = b * 256 + t;                          // frag id 0..4095
    const int l  = q & 63;
    const int ks = (q >> 6) & 3;
    const int nt = q >> 8;                               // n-tile 0..15
    const int kb = ks * 32 + (l >> 4) * 8;
    const int col = nt * 16 + (l & 15);
    uint32_t d[4];
    #pragma unroll
    for (int p = 0; p < 4; p++) {
        uint32_t lo = f2bf_rne(W[(size_t)(kb + 2 * p    ) * FOUT + col]);
        uint32_t hi = f2bf_rne(W[(size_t)(kb + 2 * p + 1) * FOUT + col]);
        d[p] = lo | (hi << 16);
    }
    ((uint4*)(ws + WSFRAG))[q] = make_uint4(d[0], d[1], d[2], d[3]);
}

// 512 blocks (one per bt-slab), full F per block; wave w: 64 channels,
// 2 m-tiles x 4 n-tiles x 4 k-steps = 32 MFMAs. Pre-norm y stored bf16 in ws.
__global__ __launch_bounds__(256) void k_conv(const float* __restrict__ x,
                                              float* ws)
{
    __shared__ uint16_t asB[32 * AROW];    // 8.7 KB bf16 A, pre-shifted
    __shared__ float sumL[FOUT], sqL[FOUT];

    const int bt = blockIdx.x;
    const int t  = threadIdx.x;

    const int w     = t >> 6;              // wave id -> channel group w*64
    const int l     = t & 63;
    const int row16 = l & 15;
    const int koct  = l >> 4;

    // B fragments FIRST: 16 dwordx4/lane; L2 latency overlaps staging below.
    const uint4* wsw = (const uint4*)(ws + WSFRAG);
    uint4 bu[4][4];
    #pragma unroll
    for (int nt = 0; nt < 4; nt++)
        #pragma unroll
        for (int ks = 0; ks < 4; ks++)
            bu[nt][ks] = wsw[(((w * 4 + nt) * 4 + ks) << 6) + l];

    // ---------- stage shifted bf16 A-slab (float4 loads) ----------
    for (int i = t; i < 704; i += 256) {   // zero pad rows 21..31
        int r  = 21 + (i >> 6);
        int c2 = (i & 63) << 1;
        *(uint32_t*)&asB[r * AROW + c2] = 0u;
    }
    const float4* xin4 = (const float4*)(x + (size_t)bt * (NPOS * CIN));
    for (int i = t; i < (NPOS * CIN) / 4; i += 256) {    // 672 dwordx4/block
        float4 v = xin4[i];                // fully coalesced 16B load
        int base = i << 2;                 // element index = r*128 + c
        int r = base >> 7;
        int c = base & (CIN - 1);
        int s = c % NPOS;                  // shift for c (c..c+3 same r: c<=124)
        int n0 = r + s; if (n0 >= NPOS) n0 -= NPOS;
        int n1 = n0 + 1; if (n1 >= NPOS) n1 -= NPOS;   // s+1 (c%21 wraps fold
        int n2 = n1 + 1; if (n2 >= NPOS) n2 -= NPOS;   //  into same mod ring:
        int n3 = n2 + 1; if (n3 >= NPOS) n3 -= NPOS;   //  n_{j+1}=(n_j+1)%21)
        asB[n0 * AROW + c    ] = f2bf_rne(v.x);
        asB[n1 * AROW + c + 1] = f2bf_rne(v.y);
        asB[n2 * AROW + c + 2] = f2bf_rne(v.z);
        asB[n3 * AROW + c + 3] = f2bf_rne(v.w);
    }

    v8s bfr[4][4];
    #pragma unroll
    for (int nt = 0; nt < 4; nt++)
        #pragma unroll
        for (int ks = 0; ks < 4; ks++)
            bfr[nt][ks] = __builtin_bit_cast(v8s, bu[nt][ks]);
    __syncthreads();

    // ---------- MFMA ----------
    v4f acc[2][4];
    #pragma unroll
    for (int m = 0; m < 2; m++)
        #pragma unroll
        for (int nt = 0; nt < 4; nt++) acc[m][nt] = (v4f){0.f, 0.f, 0.f, 0.f};

    #pragma unroll
    for (int m = 0; m < 2; m++) {
        v8s afr[4];
        #pragma unroll
        for (int ks = 0; ks < 4; ks++)     // ds_read_b128, 16B-aligned
            afr[ks] = *(const v8s*)&asB[(m * 16 + row16) * AROW + ks * 32 + koct * 8];
        #pragma unroll
        for (int ks = 0; ks < 4; ks++)
            #pragma unroll
            for (int nt = 0; nt < 4; nt++)
                acc[m][nt] = __builtin_amdgcn_mfma_f32_16x16x32_bf16(
                                 afr[ks], bfr[nt][ks], acc[m][nt], 0, 0, 0);
    }

    // ---------- bf16 y store (pre-norm) + per-channel sums ----------
    uint16_t* yws = (uint16_t*)(ws + WSY);
    uint16_t* yout = yws + (size_t)bt * (NPOS * FOUT) + w * 64;
    #pragma unroll
    for (int nt = 0; nt < 4; nt++) {
        float s = 0.f, q = 0.f;
        #pragma unroll
        for (int m = 0; m < 2; m++)
            #pragma unroll
            for (int rg = 0; rg < 4; rg++) {
                float v = acc[m][nt][rg];  // pad rows contribute exactly 0
                s += v; q += v * v;
                int gr = m * 16 + koct * 4 + rg;   // C/D: col=row16, row=koct*4+rg
                if (gr < NPOS)
                    yout[(size_t)gr * FOUT + nt * 16 + row16] = f2bf_rne(v);
            }
        s += __shfl_xor(s, 16); s += __shfl_xor(s, 32);
        q += __shfl_xor(q, 16); q += __shfl_xor(q, 32);
        if (l < 16) {
            sumL[w * 64 + nt * 16 + l] = s;
            sqL [w * 64 + nt * 16 + l] = q;
        }
    }
    __syncthreads();

    // 32-way spread: 16 adds/address
    float* part = ws + (bt & (PARTS - 1)) * 512;
    atomicAdd(part + t, sumL[t]);
    atomicAdd(part + 256 + t, sqL[t]);
}

// 672 blocks: each handles 16 m-rows. sc/bs once per block into LDS
// (coalesced partial reads), then 2 iterations of bf16->f32 normalize.
__global__ __launch_bounds__(256) void k_bnapply(const float* __restrict__ ws,
                                                 const float* __restrict__ gamma,
                                                 const float* __restrict__ beta,
                                                 float* __restrict__ y)
{
    __shared__ float scL[FOUT], bsL[FOUT];
    const int t = threadIdx.x;

    {   // channel t: sum the 32 partials (coalesced: consecutive t)
        float s = 0.f, q = 0.f;
        #pragma unroll
        for (int p = 0; p < PARTS; p++) {
            s += ws[p * 512 + t];
            q += ws[p * 512 + 256 + t];
        }
        const float invM = 1.0f / (float)M_TOTAL;
        float mean = s * invM;
        float var  = fmaf(-mean, mean, q * invM);
        float sc   = rsqrtf(var + BN_EPS) * gamma[t];
        scL[t] = sc;
        bsL[t] = beta[t] - mean * sc;
    }
    __syncthreads();

    const int fb = (t & 31) << 3;          // this thread's 8-channel base
    const uint16_t* yws = (const uint16_t*)(ws + WSY);
    const float4 sc0 = *(const float4*)&scL[fb];
    const float4 sc1 = *(const float4*)&scL[fb + 4];
    const float4 bs0 = *(const float4*)&bsL[fb];
    const float4 bs1 = *(const float4*)&bsL[fb + 4];

    #pragma unroll
    for (int it = 0; it < 2; it++) {
        int m = blockIdx.x * 16 + it * 8 + (t >> 5);
        uint4 u = *(const uint4*)(yws + (size_t)m * FOUT + fb);
        float4 o0, o1;
        o0.x = fmaxf(fmaf(bf2f_lo(u.x), sc0.x, bs0.x), 0.0f);
        o0.y = fmaxf(fmaf(bf2f_hi(u.x), sc0.y, bs0.y), 0.0f);
        o0.z = fmaxf(fmaf(bf2f_lo(u.y), sc0.z, bs0.z), 0.0f);
        o0.w = fmaxf(fmaf(bf2f_hi(u.y), sc0.w, bs0.w), 0.0f);
        o1.x = fmaxf(fmaf(bf2f_lo(u.z), sc1.x, bs1.x), 0.0f);
        o1.y = fmaxf(fmaf(bf2f_hi(u.z), sc1.y, bs1.y), 0.0f);
        o1.z = fmaxf(fmaf(bf2f_lo(u.w), sc1.z, bs1.z), 0.0f);
        o1.w = fmaxf(fmaf(bf2f_hi(u.w), sc1.w, bs1.w), 0.0f);
        float* yo = y + (size_t)m * FOUT + fb;
        *(float4*)yo       = o0;
        *(float4*)(yo + 4) = o1;
    }
}

// Template-named symbol kept defined (harness-compat; not launched).
extern "C" __global__ void SpatialShiftConvBlock_71923522339050_kernel() {}

extern "C" void kernel_launch(void* const* d_in, const int* in_sizes, int n_in,
                              void* d_out, int out_size, void* d_ws, size_t ws_size,
                              hipStream_t stream) {
    float* y  = (float*)d_out;             // FLOAT32 output
    float* ws = (float*)d_ws;              // 32x partials | W frags | bf16 y
    k_prep<<<16, 256, 0, stream>>>((const float*)d_in[1], ws);
    k_conv<<<BT, 256, 0, stream>>>((const float*)d_in[0], ws);
    k_bnapply<<<672, 256, 0, stream>>>(ws, (const float*)d_in[3],
                                       (const float*)d_in[4], y);
}